// Round 1
// baseline (168.322 us; speedup 1.0000x reference)
//
#include <hip/hip_runtime.h>

#define N_NODES 100000
#define DEG 16
#define D_FEAT 64
// D_FEAT = 64 floats = 16 float4 per row; 16 lanes cooperate on one row.

__global__ __launch_bounds__(256) void spmm_hop_kernel(
    const float4* __restrict__ x4,      // [N_NODES * 16] float4
    const float*  __restrict__ values,  // [N_NODES * DEG]
    const int*    __restrict__ indices, // [N_NODES * DEG]
    float4*       __restrict__ out4)    // [N_NODES * 16] float4
{
    const int tid  = blockIdx.x * blockDim.x + threadIdx.x;
    const int row  = tid >> 4;   // 16 lanes per row
    const int lane = tid & 15;
    if (row >= N_NODES) return;

    const int base = row * DEG;
    float4 acc = make_float4(0.f, 0.f, 0.f, 0.f);

    #pragma unroll
    for (int j = 0; j < DEG; ++j) {
        const int   idx = indices[base + j];   // 16-lane broadcast load
        const float v   = values[base + j];    // 16-lane broadcast load
        const float4 xv = x4[(size_t)idx * 16 + lane];  // coalesced 256B row gather
        acc.x += v * xv.x;
        acc.y += v * xv.y;
        acc.z += v * xv.z;
        acc.w += v * xv.w;
    }
    out4[(size_t)row * 16 + lane] = acc;
}

extern "C" void kernel_launch(void* const* d_in, const int* in_sizes, int n_in,
                              void* d_out, int out_size, void* d_ws, size_t ws_size,
                              hipStream_t stream) {
    const float* x       = (const float*)d_in[0];  // [N_NODES, 64] f32
    const float* values  = (const float*)d_in[1];  // [N_EDGES] f32
    // d_in[2] = indptr (degenerate fixed-degree CSR) — unused
    const int*   indices = (const int*)d_in[3];    // [N_EDGES] int32 (harness convention)

    float* out = (float*)d_out;                    // [N_NODES, 64] f32
    float* ws  = (float*)d_ws;                     // >= 25.6 MB scratch

    const int threads = N_NODES * 16;              // 16 lanes per row
    const int block   = 256;
    const int grid    = (threads + block - 1) / block;

    // hop 1: x -> out
    spmm_hop_kernel<<<grid, block, 0, stream>>>(
        (const float4*)x, values, indices, (float4*)out);
    // hop 2: out -> ws
    spmm_hop_kernel<<<grid, block, 0, stream>>>(
        (const float4*)out, values, indices, (float4*)ws);
    // hop 3: ws -> out
    spmm_hop_kernel<<<grid, block, 0, stream>>>(
        (const float4*)ws, values, indices, (float4*)out);
}